// Round 3
// baseline (355.735 us; speedup 1.0000x reference)
//
#include <hip/hip_runtime.h>
#include <math.h>

#define BROWS 65536
#define LLEN  1024
#define KW    16
#define NPOS  (LLEN - KW + 1)   // 1009 valid conv outputs
#define RPB   4                 // rows (= waves) per block

// XOR swizzle on float4-granule index: involution, keeps 16B alignment,
// spreads bank-start quads across every 8 consecutive lanes for both the
// staging writes (lane-contiguous granules) and the window reads
// (granule = 4*lane + j).
__device__ __forceinline__ int swz(int g) { return g ^ ((g >> 3) & 7); }

__global__ __launch_bounds__(256, 8) void conv_pool_classify(
    const float* __restrict__ x,       // (B, 1, L)
    const float* __restrict__ w,       // (1, 1, K)
    const float* __restrict__ bias,    // (1,)
    const float* __restrict__ ranges,  // (4, 2) row-major
    int* __restrict__ out)             // (B,1,1) labels as int32
{
    __shared__ float4 lds[RPB][LLEN / 4];   // 4 KB per row, 16 KB total

    const int lane = threadIdx.x & 63;
    const int wid  = threadIdx.x >> 6;
    const int row  = blockIdx.x * RPB + wid;
    const float* __restrict__ xr = x + (size_t)row * LLEN;

    // ---- filter (lane-uniform -> scalar loads) ----
    float wv[KW];
#pragma unroll
    for (int k = 0; k < KW; ++k) wv[k] = w[k];

    // ---- stage row to LDS, fully coalesced: lane-contiguous float4s ----
#pragma unroll
    for (int s = 0; s < 4; ++s) {
        const int g = 64 * s + lane;                 // granule index
        lds[wid][swz(g)] = *(const float4*)(xr + 4 * g);
    }
    __syncthreads();

    // ---- each lane pulls its 32-float window (granules 4*lane .. 4*lane+7) ----
    float xv[32];
#pragma unroll
    for (int j = 0; j < 8; ++j) {
        int g = 4 * lane + j;
        if (g > 255) g = 255;                        // lane 63 tail clamp (unused values)
        *(float4*)(&xv[4 * j]) = lds[wid][swz(g)];
    }

    // ---- 16 conv outputs per lane, running max, tail predicated ----
    const int own = 16 * lane;
    float vmax = -INFINITY;
#pragma unroll
    for (int p = 0; p < KW; ++p) {
        float acc = 0.0f;
#pragma unroll
        for (int k = 0; k < KW; ++k) acc = fmaf(xv[p + k], wv[k], acc);
        const bool valid = (own + p) < NPOS;         // only lane 63 has invalid p>0
        vmax = valid ? fmaxf(vmax, acc) : vmax;
    }

    // ---- wave-wide max reduction ----
#pragma unroll
    for (int off = 32; off > 0; off >>= 1)
        vmax = fmaxf(vmax, __shfl_xor(vmax, off, 64));

    // ---- lane 0: bias + relu + classify + store ----
    if (lane == 0) {
        const float v = fmaxf(vmax + bias[0], 0.0f);

        int label = -1;
#pragma unroll
        for (int j = 0; j < 4; ++j) {
            const float lo = ranges[2 * j];
            const float hi = ranges[2 * j + 1];
            if (label < 0 && v >= lo && v <= hi) label = j;  // first match
        }
        if (label < 0) {
            float best = INFINITY;
            int bj = 0;
#pragma unroll
            for (int j = 0; j < 8; ++j) {
                const float d = sqrtf(v * v + ranges[j]);
                if (d < best) { best = d; bj = j; }
            }
            label = bj >> 1;
        }
        out[row] = label;
    }
}

extern "C" void kernel_launch(void* const* d_in, const int* in_sizes, int n_in,
                              void* d_out, int out_size, void* d_ws, size_t ws_size,
                              hipStream_t stream) {
    const float* x      = (const float*)d_in[0];
    const float* w      = (const float*)d_in[1];
    const float* bias   = (const float*)d_in[2];
    const float* ranges = (const float*)d_in[3];
    int* out = (int*)d_out;

    dim3 grid(BROWS / RPB);   // 16384 blocks, 4 waves each = 1 row/wave
    dim3 block(256);
    conv_pool_classify<<<grid, block, 0, stream>>>(x, w, bias, ranges, out);
}

// Round 5
// 343.069 us; speedup vs baseline: 1.0369x; 1.0369x over previous
//
#include <hip/hip_runtime.h>
#include <math.h>

#define BROWS 65536
#define LLEN  1024
#define KW    16
#define NPOS  (LLEN - KW + 1)     // 1009 valid conv outputs
#define RPB   4                   // waves per block (independent, no barrier)
#define NBLOCKS 2048
#define ROWS_PER_WAVE (BROWS / (NBLOCKS * RPB))   // 8

// Native vector type for __builtin_nontemporal_load (HIP_vector_type rejected).
typedef float nt_float4 __attribute__((ext_vector_type(4)));

// XOR swizzle on float4-granule index: involution, keeps 16B alignment,
// spreads bank-start quads so both staging writes (lane-contiguous) and
// window reads (granule = 4*lane+j) are near-conflict-free.
__device__ __forceinline__ int swz(int g) { return g ^ ((g >> 3) & 7); }

__global__ __launch_bounds__(256) void conv_pool_classify(
    const float* __restrict__ x,       // (B, 1, L)
    const float* __restrict__ w,       // (1, 1, K)
    const float* __restrict__ bias,    // (1,)
    const float* __restrict__ ranges,  // (4, 2) row-major
    int* __restrict__ out)             // (B,1,1) labels as int32
{
    __shared__ nt_float4 lds[RPB][LLEN / 4];   // 4 KB private per wave

    const int lane = threadIdx.x & 63;
    const int wid  = threadIdx.x >> 6;
    const int wave = blockIdx.x * RPB + wid;
    const int row0 = wave * ROWS_PER_WAVE;

    // ---- filter (lane-uniform -> scalar loads) ----
    float wv[KW];
#pragma unroll
    for (int k = 0; k < KW; ++k) wv[k] = w[k];

    // ---- prefetch first row into registers (nontemporal: streamed once) ----
    nt_float4 p[4];
    {
        const float* __restrict__ xr = x + (size_t)row0 * LLEN;
#pragma unroll
        for (int s = 0; s < 4; ++s)
            p[s] = __builtin_nontemporal_load((const nt_float4*)(xr + 256 * s + 4 * lane));
    }

    for (int it = 0; it < ROWS_PER_WAVE; ++it) {
        const int row = row0 + it;

        // ---- stage prefetched row to this wave's private LDS region ----
        // (same-wave ds_write -> ds_read is in-order via lgkmcnt; no barrier)
#pragma unroll
        for (int s = 0; s < 4; ++s)
            lds[wid][swz(64 * s + lane)] = p[s];

        // ---- issue next row's global loads; they fly during compute ----
        if (it + 1 < ROWS_PER_WAVE) {
            const float* __restrict__ xr = x + (size_t)(row + 1) * LLEN;
#pragma unroll
            for (int s = 0; s < 4; ++s)
                p[s] = __builtin_nontemporal_load((const nt_float4*)(xr + 256 * s + 4 * lane));
        }

        // ---- each lane pulls its 32-float window from LDS ----
        float xv[32];
#pragma unroll
        for (int j = 0; j < 8; ++j) {
            int g = 4 * lane + j;
            if (g > 255) g = 255;            // lane 63 tail clamp (values unused)
            *(nt_float4*)(&xv[4 * j]) = lds[wid][swz(g)];
        }

        // ---- 16 conv outputs per lane, running max, tail predicated ----
        const int own = 16 * lane;
        float vmax = -INFINITY;
#pragma unroll
        for (int pp = 0; pp < KW; ++pp) {
            float acc = 0.0f;
#pragma unroll
            for (int k = 0; k < KW; ++k) acc = fmaf(xv[pp + k], wv[k], acc);
            vmax = ((own + pp) < NPOS) ? fmaxf(vmax, acc) : vmax;
        }

        // ---- wave-wide max reduction ----
#pragma unroll
        for (int off = 32; off > 0; off >>= 1)
            vmax = fmaxf(vmax, __shfl_xor(vmax, off, 64));

        // ---- lane 0: bias + relu + classify + store ----
        if (lane == 0) {
            const float v = fmaxf(vmax + bias[0], 0.0f);

            int label = -1;
#pragma unroll
            for (int j = 0; j < 4; ++j) {
                const float lo = ranges[2 * j];
                const float hi = ranges[2 * j + 1];
                if (label < 0 && v >= lo && v <= hi) label = j;  // first match
            }
            if (label < 0) {
                float best = INFINITY;
                int bj = 0;
#pragma unroll
                for (int j = 0; j < 8; ++j) {
                    const float d = sqrtf(v * v + ranges[j]);
                    if (d < best) { best = d; bj = j; }
                }
                label = bj >> 1;
            }
            out[row] = label;
        }
    }
}

extern "C" void kernel_launch(void* const* d_in, const int* in_sizes, int n_in,
                              void* d_out, int out_size, void* d_ws, size_t ws_size,
                              hipStream_t stream) {
    const float* x      = (const float*)d_in[0];
    const float* w      = (const float*)d_in[1];
    const float* bias   = (const float*)d_in[2];
    const float* ranges = (const float*)d_in[3];
    int* out = (int*)d_out;

    dim3 grid(NBLOCKS);   // 2048 blocks x 4 waves x 8 rows/wave = 65536 rows
    dim3 block(256);
    conv_pool_classify<<<grid, block, 0, stream>>>(x, w, bias, ranges, out);
}